// Round 2
// baseline (919.752 us; speedup 1.0000x reference)
//
#include <hip/hip_runtime.h>

// MeshSDFLoss: P=16384 points vs F=16384 triangles, min sqdist + argmin + loss.
// Outputs (flat float32): [0]=loss, [1..P]=dist, [1+P..1+2P]=assoc (as float).
//
// Correctness strategy: bit-exact replication of the numpy fp32 reference on
// the SELECTED Ericson region: every mul/add/sub/div in the distance chain
// uses __f*_rn intrinsics (unfusable, correctly rounded IEEE fp32), so no FMA
// contraction can flip region signs (va_/vb_/vc_) or distance ULPs.
// Only the selected region's division is computed (priority a>b>c>ab>ac>bc>
// interior == the reference's where-override order); its rounding is
// identical to the reference's. Argmin tie-break = first index: strict-<
// scan within a chunk + packed (distbits<<32|idx) u64 atomicMin across
// chunks (equal dist bits -> smaller index wins == np.argmin first match).

#define PTOT 16384
#define FTOT 16384
#define NCHUNK 16
#define FCHUNK (FTOT / NCHUNK)   // 1024 faces per chunk
#define TILE 256
#define BLOCK 256
#define FSTRIDE 20               // floats per staged face (16B aligned)

__global__ __launch_bounds__(BLOCK) void sdf_main_kernel(
    const float* __restrict__ verts,
    const int* __restrict__ faces,
    const float* __restrict__ points,
    unsigned long long* __restrict__ best)
{
#pragma clang fp contract(off)
    // Per-face record: [ax,ay,az,bx][by,bz,cx,cy][cz,abx,aby,abz][acx,acy,acz,cbx][cby,cbz,0,0]
    __shared__ float sF[TILE * FSTRIDE];

    const int p = blockIdx.x * BLOCK + threadIdx.x;
    const float px = points[p * 3 + 0];
    const float py = points[p * 3 + 1];
    const float pz = points[p * 3 + 2];

    float bestd = __builtin_inff();
    int   besti = 0;

    const int fbase = blockIdx.y * FCHUNK;

    for (int t0 = 0; t0 < FCHUNK; t0 += TILE) {
        __syncthreads();
        {
            const int f  = fbase + t0 + threadIdx.x;   // TILE == BLOCK
            const int i0 = faces[f * 3 + 0];
            const int i1 = faces[f * 3 + 1];
            const int i2 = faces[f * 3 + 2];
            const float ax = verts[i0 * 3 + 0], ay = verts[i0 * 3 + 1], az = verts[i0 * 3 + 2];
            const float bx = verts[i1 * 3 + 0], by = verts[i1 * 3 + 1], bz = verts[i1 * 3 + 2];
            const float cx = verts[i2 * 3 + 0], cy = verts[i2 * 3 + 1], cz = verts[i2 * 3 + 2];
            float* s = &sF[threadIdx.x * FSTRIDE];
            s[0]  = ax;      s[1]  = ay;      s[2]  = az;      s[3]  = bx;
            s[4]  = by;      s[5]  = bz;      s[6]  = cx;      s[7]  = cy;
            s[8]  = cz;
            s[9]  = __fsub_rn(bx, ax); s[10] = __fsub_rn(by, ay); s[11] = __fsub_rn(bz, az); // ab
            s[12] = __fsub_rn(cx, ax); s[13] = __fsub_rn(cy, ay); s[14] = __fsub_rn(cz, az); // ac
            s[15] = __fsub_rn(cx, bx); s[16] = __fsub_rn(cy, by); s[17] = __fsub_rn(cz, bz); // cb
            s[18] = 0.0f;    s[19] = 0.0f;
        }
        __syncthreads();

#pragma unroll 2
        for (int j = 0; j < TILE; ++j) {
            const float4* s4 = (const float4*)&sF[j * FSTRIDE];
            const float4 r0 = s4[0], r1 = s4[1], r2 = s4[2], r3 = s4[3], r4 = s4[4];
            const float ax = r0.x,  ay = r0.y,  az = r0.z;
            const float bx = r0.w,  by = r1.x,  bz = r1.y;
            const float cx = r1.z,  cy = r1.w,  cz = r2.x;
            const float abx = r2.y, aby = r2.z, abz = r2.w;
            const float acx = r3.x, acy = r3.y, acz = r3.z;
            const float cbx = r3.w, cby = r4.x, cbz = r4.y;

            const float apx = __fsub_rn(px, ax), apy = __fsub_rn(py, ay), apz = __fsub_rn(pz, az);
            const float d1 = __fadd_rn(__fadd_rn(__fmul_rn(abx, apx), __fmul_rn(aby, apy)), __fmul_rn(abz, apz));
            const float d2 = __fadd_rn(__fadd_rn(__fmul_rn(acx, apx), __fmul_rn(acy, apy)), __fmul_rn(acz, apz));
            const float bpx = __fsub_rn(px, bx), bpy = __fsub_rn(py, by), bpz = __fsub_rn(pz, bz);
            const float d3 = __fadd_rn(__fadd_rn(__fmul_rn(abx, bpx), __fmul_rn(aby, bpy)), __fmul_rn(abz, bpz));
            const float d4 = __fadd_rn(__fadd_rn(__fmul_rn(acx, bpx), __fmul_rn(acy, bpy)), __fmul_rn(acz, bpz));
            const float cpx = __fsub_rn(px, cx), cpy = __fsub_rn(py, cy), cpz = __fsub_rn(pz, cz);
            const float d5 = __fadd_rn(__fadd_rn(__fmul_rn(abx, cpx), __fmul_rn(aby, cpy)), __fmul_rn(abz, cpz));
            const float d6 = __fadd_rn(__fadd_rn(__fmul_rn(acx, cpx), __fmul_rn(acy, cpy)), __fmul_rn(acz, cpz));

            const float vc_ = __fsub_rn(__fmul_rn(d1, d4), __fmul_rn(d3, d2));
            const float vb_ = __fsub_rn(__fmul_rn(d5, d2), __fmul_rn(d1, d6));
            const float va_ = __fsub_rn(__fmul_rn(d3, d6), __fmul_rn(d5, d4));

            const float den_ab = __fsub_rn(d1, d3);
            const float den_ac = __fsub_rn(d2, d6);
            const float t43    = __fsub_rn(d4, d3);
            const float t56    = __fsub_rn(d5, d6);
            const float den_bc = __fadd_rn(t43, t56);
            const float den_in = __fadd_rn(__fadd_rn(va_, vb_), vc_);

            // Region flags (reference's where-chain priority: a>b>c>ab>ac>bc>interior)
            const bool f_a  = (d1 <= 0.0f) && (d2 <= 0.0f);
            const bool f_b  = (d3 >= 0.0f) && (d4 <= d3);
            const bool f_c  = (d6 >= 0.0f) && (d5 <= d6);
            const bool f_ab = (vc_ <= 0.0f) && (d1 >= 0.0f) && (d3 <= 0.0f);
            const bool f_ac = (vb_ <= 0.0f) && (d2 >= 0.0f) && (d6 <= 0.0f);
            const bool f_bc = (va_ <= 0.0f) && (t43 >= 0.0f) && (t56 >= 0.0f);
            const bool vert = f_a || f_b || f_c;
            const bool e_ab = f_ab && !vert;
            const bool e_ac = f_ac && !vert && !f_ab;
            const bool e_bc = f_bc && !vert && !f_ab && !f_ac;

            // Single division: select the surviving region's num/den (rounding
            // identical to the reference's per-region division).
            const float num  = e_ab ? d1 : (e_ac ? d2 : (e_bc ? t43 : 1.0f));
            const float denr = e_ab ? den_ab : (e_ac ? den_ac : (e_bc ? den_bc : den_in));
            const float den  = (denr != 0.0f) ? denr : 1.0f;
            const float t    = __fdiv_rn(num, den);

            // Interior candidate (t == inv when interior; garbage otherwise, overridden)
            const float v_in = __fmul_rn(vb_, t);
            const float w_in = __fmul_rn(vc_, t);
            float qx = __fadd_rn(__fadd_rn(ax, __fmul_rn(abx, v_in)), __fmul_rn(acx, w_in));
            float qy = __fadd_rn(__fadd_rn(ay, __fmul_rn(aby, v_in)), __fmul_rn(acy, w_in));
            float qz = __fadd_rn(__fadd_rn(az, __fmul_rn(abz, v_in)), __fmul_rn(acz, w_in));

            qx = e_bc ? __fadd_rn(bx, __fmul_rn(cbx, t)) : qx;
            qy = e_bc ? __fadd_rn(by, __fmul_rn(cby, t)) : qy;
            qz = e_bc ? __fadd_rn(bz, __fmul_rn(cbz, t)) : qz;

            qx = e_ac ? __fadd_rn(ax, __fmul_rn(acx, t)) : qx;
            qy = e_ac ? __fadd_rn(ay, __fmul_rn(acy, t)) : qy;
            qz = e_ac ? __fadd_rn(az, __fmul_rn(acz, t)) : qz;

            qx = e_ab ? __fadd_rn(ax, __fmul_rn(abx, t)) : qx;
            qy = e_ab ? __fadd_rn(ay, __fmul_rn(aby, t)) : qy;
            qz = e_ab ? __fadd_rn(az, __fmul_rn(abz, t)) : qz;

            qx = f_c ? cx : qx;  qy = f_c ? cy : qy;  qz = f_c ? cz : qz;
            qx = f_b ? bx : qx;  qy = f_b ? by : qy;  qz = f_b ? bz : qz;
            qx = f_a ? ax : qx;  qy = f_a ? ay : qy;  qz = f_a ? az : qz;

            const float dxx = __fsub_rn(px, qx), dyy = __fsub_rn(py, qy), dzz = __fsub_rn(pz, qz);
            const float dist = __fadd_rn(__fadd_rn(__fmul_rn(dxx, dxx), __fmul_rn(dyy, dyy)), __fmul_rn(dzz, dzz));

            if (dist < bestd) { bestd = dist; besti = fbase + t0 + j; }
        }
    }

    const unsigned long long packed =
        ((unsigned long long)__float_as_uint(bestd) << 32) | (unsigned int)besti;
    atomicMin(&best[p], packed);
}

__global__ __launch_bounds__(BLOCK) void sdf_final_kernel(
    const unsigned long long* __restrict__ best, float* __restrict__ out)
{
    __shared__ float wsum[BLOCK / 64];
    const int p = blockIdx.x * BLOCK + threadIdx.x;
    const unsigned long long v = best[p];
    const float d = __uint_as_float((unsigned int)(v >> 32));
    const int idx = (int)(unsigned int)(v & 0xffffffffull);
    out[1 + p] = d;
    out[1 + PTOT + p] = (float)idx;

    float s = d;
    for (int off = 32; off > 0; off >>= 1) s += __shfl_down(s, off, 64);
    const int lane = threadIdx.x & 63;
    const int w = threadIdx.x >> 6;
    if (lane == 0) wsum[w] = s;
    __syncthreads();
    if (threadIdx.x == 0) {
        float tsum = 0.0f;
        for (int i = 0; i < BLOCK / 64; ++i) tsum += wsum[i];
        atomicAdd(&out[0], tsum);
    }
}

extern "C" void kernel_launch(void* const* d_in, const int* in_sizes, int n_in,
                              void* d_out, int out_size, void* d_ws, size_t ws_size,
                              hipStream_t stream) {
    const float* verts  = (const float*)d_in[0];
    const int*   faces  = (const int*)d_in[1];
    const float* points = (const float*)d_in[2];
    float* out = (float*)d_out;
    unsigned long long* best = (unsigned long long*)d_ws;

    // 0xFF... = max u64, larger than any packed (finite dist, idx) result.
    hipMemsetAsync(best, 0xFF, (size_t)PTOT * sizeof(unsigned long long), stream);
    hipMemsetAsync(out, 0, sizeof(float), stream);  // loss accumulator

    dim3 grid(PTOT / BLOCK, NCHUNK);
    sdf_main_kernel<<<grid, BLOCK, 0, stream>>>(verts, faces, points, best);
    sdf_final_kernel<<<PTOT / BLOCK, BLOCK, 0, stream>>>(best, out);
}

// Round 3
// 387.127 us; speedup vs baseline: 2.3758x; 2.3758x over previous
//
#include <hip/hip_runtime.h>

// MeshSDFLoss: P=16384 points vs F=16384 triangles, min sqdist + argmin + loss.
// Outputs (flat float32): [0]=loss, [1..P]=dist, [1+P..1+2P]=assoc (as float).
//
// R3: wave-unanimous conservative pruning on Morton-sorted points.
//  - Executed pairs remain BIT-EXACT vs the numpy fp32 reference (__f*_rn
//    chain identical to R2; unified q-selection preserves selected-path
//    rounding; trailing +/-0 terms cannot change (p-q)^2).
//  - Prune is strictly conservative: skip face j only if a LOWER BOUND on
//    dist(p, tri_j) strictly exceeds an ACHIEVED distance (local best or
//    cross-chunk atomic best), with 1e-4 rel + 1e-5 abs safety margins.
//    Then dist_j > min ==> j can never be the (first-index) argmin. Ties and
//    tie-break order are untouched.
//  - Points Morton-sorted (4096-bin counting sort, on-device) so the 64
//    lanes of a wave hold a compact spatial cluster -> __all(skip) fires.

#define PTOT 16384
#define FTOT 16384
#define NCHUNK 16
#define FCHUNK (FTOT / NCHUNK)   // 1024 faces per chunk
#define TILE 256
#define BLOCK 256
#define FSTRIDE 24               // floats per staged face (16B aligned)
#define NBINS 4096               // 4 bits per axis Morton

// ws layout (bytes):
//   best      [0,        131072)   PTOT * u64
//   sortedPts [131072,   393216)   PTOT * uint4 {xbits,ybits,zbits,pid}
//   hist      [393216,   409600)   NBINS * u32
#define WS_BEST   0
#define WS_SORTED 131072
#define WS_HIST   393216

__device__ __forceinline__ unsigned morton12(float x, float y, float z) {
    int ix = (int)(x * 16.0f); ix = ix < 0 ? 0 : (ix > 15 ? 15 : ix);
    int iy = (int)(y * 16.0f); iy = iy < 0 ? 0 : (iy > 15 ? 15 : iy);
    int iz = (int)(z * 16.0f); iz = iz < 0 ? 0 : (iz > 15 ? 15 : iz);
    unsigned code = 0;
#pragma unroll
    for (int k = 0; k < 4; ++k) {
        code |= (((unsigned)(ix >> k) & 1u) << (3 * k + 2))
              | (((unsigned)(iy >> k) & 1u) << (3 * k + 1))
              | (((unsigned)(iz >> k) & 1u) << (3 * k + 0));
    }
    return code;
}

__global__ __launch_bounds__(BLOCK) void hist_kernel(
    const float* __restrict__ points, unsigned* __restrict__ hist)
{
    const int p = blockIdx.x * BLOCK + threadIdx.x;
    const unsigned c = morton12(points[p * 3], points[p * 3 + 1], points[p * 3 + 2]);
    atomicAdd(&hist[c], 1u);
}

__global__ __launch_bounds__(256) void scan_kernel(unsigned* __restrict__ hist)
{
    // 256 threads, 16 bins each: exclusive scan over NBINS.
    __shared__ unsigned ps[256];
    const int t = threadIdx.x;
    unsigned local[16];
    unsigned run = 0;
#pragma unroll
    for (int i = 0; i < 16; ++i) {
        unsigned v = hist[t * 16 + i];
        local[i] = run;
        run += v;
    }
    ps[t] = run;
    __syncthreads();
    for (int off = 1; off < 256; off <<= 1) {
        unsigned v = (t >= off) ? ps[t - off] : 0u;
        __syncthreads();
        ps[t] += v;
        __syncthreads();
    }
    const unsigned base = (t == 0) ? 0u : ps[t - 1];
#pragma unroll
    for (int i = 0; i < 16; ++i) hist[t * 16 + i] = base + local[i];
}

__global__ __launch_bounds__(BLOCK) void scatter_kernel(
    const float* __restrict__ points, unsigned* __restrict__ hist,
    uint4* __restrict__ sorted)
{
    const int p = blockIdx.x * BLOCK + threadIdx.x;
    const float x = points[p * 3], y = points[p * 3 + 1], z = points[p * 3 + 2];
    const unsigned c = morton12(x, y, z);
    const unsigned pos = atomicAdd(&hist[c], 1u);
    sorted[pos] = make_uint4(__float_as_uint(x), __float_as_uint(y),
                             __float_as_uint(z), (unsigned)p);
}

__global__ __launch_bounds__(BLOCK) void sdf_main_kernel(
    const float* __restrict__ verts,
    const int* __restrict__ faces,
    const uint4* __restrict__ sortedPts,
    unsigned long long* __restrict__ best)
{
#pragma clang fp contract(off)
    // Face record (24 floats): a(3) b(3) c(3) ab(3) ac(3) cb(3) nhat(3) Ra pad2
    __shared__ float sF[TILE * FSTRIDE];

    const uint4 sp = sortedPts[blockIdx.x * BLOCK + threadIdx.x];
    const float px = __uint_as_float(sp.x);
    const float py = __uint_as_float(sp.y);
    const float pz = __uint_as_float(sp.z);
    const int  pid = (int)sp.w;

    float bestd = __builtin_inff();
    int   besti = 0;
    float pruneS = __builtin_inff();   // sqrt of best achieved distance
    float pThr   = __builtin_inff();   // plane-prune threshold

    const int fbase = blockIdx.y * FCHUNK;

    for (int t0 = 0; t0 < FCHUNK; t0 += TILE) {
        __syncthreads();
        {
            const int f  = fbase + t0 + threadIdx.x;   // TILE == BLOCK
            const int i0 = faces[f * 3 + 0];
            const int i1 = faces[f * 3 + 1];
            const int i2 = faces[f * 3 + 2];
            const float ax = verts[i0 * 3 + 0], ay = verts[i0 * 3 + 1], az = verts[i0 * 3 + 2];
            const float bx = verts[i1 * 3 + 0], by = verts[i1 * 3 + 1], bz = verts[i1 * 3 + 2];
            const float cx = verts[i2 * 3 + 0], cy = verts[i2 * 3 + 1], cz = verts[i2 * 3 + 2];
            const float abx = __fsub_rn(bx, ax), aby = __fsub_rn(by, ay), abz = __fsub_rn(bz, az);
            const float acx = __fsub_rn(cx, ax), acy = __fsub_rn(cy, ay), acz = __fsub_rn(cz, az);
            float* s = &sF[threadIdx.x * FSTRIDE];
            s[0]  = ax;  s[1]  = ay;  s[2]  = az;  s[3]  = bx;
            s[4]  = by;  s[5]  = bz;  s[6]  = cx;  s[7]  = cy;
            s[8]  = cz;  s[9]  = abx; s[10] = aby; s[11] = abz;
            s[12] = acx; s[13] = acy; s[14] = acz;
            s[15] = __fsub_rn(cx, bx); s[16] = __fsub_rn(cy, by); s[17] = __fsub_rn(cz, bz);
            // Prune metadata (approximate math OK; margins cover it):
            const float nx = aby * acz - abz * acy;
            const float ny = abz * acx - abx * acz;
            const float nz = abx * acy - aby * acx;
            const float nn = nx * nx + ny * ny + nz * nz;
            const float rin = rsqrtf(nn);       // nn==0 -> inf -> nhat NaN -> no plane prune
            s[18] = nx * rin; s[19] = ny * rin; s[20] = nz * rin;
            const float l1 = abx * abx + aby * aby + abz * abz;
            const float l2 = acx * acx + acy * acy + acz * acz;
            s[21] = sqrtf(fmaxf(l1, l2)) * 1.0001f + 1e-6f;   // inflated R_a
            s[22] = 0.0f; s[23] = 0.0f;
        }
        __syncthreads();

        // Refresh prune threshold from cross-chunk achieved distance.
        {
            const unsigned long long gb =
                __hip_atomic_load(&best[pid], __ATOMIC_RELAXED, __HIP_MEMORY_SCOPE_AGENT);
            const float gd = __uint_as_float((unsigned)(gb >> 32)); // sentinel = -NaN
            const float gs = sqrtf(gd);                              // NaN if unwritten
            pruneS = fminf(pruneS, gs);                              // minnum ignores NaN
            pThr   = __fmaf_rn(pruneS, 1.0002f, 1e-5f);
        }

        for (int j = 0; j < TILE; ++j) {
            const float4* s4 = (const float4*)&sF[j * FSTRIDE];
            const float4 r0 = s4[0], r4 = s4[4], r5 = s4[5];
            const float ax = r0.x, ay = r0.y, az = r0.z;

            const float apx = __fsub_rn(px, ax), apy = __fsub_rn(py, ay), apz = __fsub_rn(pz, az);

            // --- conservative lower-bound prune (sphere at a + plane) ---
            const float dap  = __fmaf_rn(apx, apx, __fmaf_rn(apy, apy, __fmul_rn(apz, apz)));
            const float sThr = (r5.y + pruneS) * 1.0002f;
            const float sTh2 = __fmaf_rn(sThr, sThr, 1e-5f);
            const float pd   = __fmaf_rn(r4.z, apx, __fmaf_rn(r4.w, apy, __fmul_rn(r5.x, apz)));
            const bool skip  = (dap > sTh2) || (fabsf(pd) > pThr);
            if (__all(skip)) continue;

            const float4 r1 = s4[1], r2 = s4[2], r3 = s4[3];
            const float bx = r0.w,  by = r1.x,  bz = r1.y;
            const float cx = r1.z,  cy = r1.w,  cz = r2.x;
            const float abx = r2.y, aby = r2.z, abz = r2.w;
            const float acx = r3.x, acy = r3.y, acz = r3.z;
            const float cbx = r3.w;
            const float cby = r4.x, cbz = r4.y;

            // --- bit-exact reference chain ---
            const float d1 = __fadd_rn(__fadd_rn(__fmul_rn(abx, apx), __fmul_rn(aby, apy)), __fmul_rn(abz, apz));
            const float d2 = __fadd_rn(__fadd_rn(__fmul_rn(acx, apx), __fmul_rn(acy, apy)), __fmul_rn(acz, apz));
            const float bpx = __fsub_rn(px, bx), bpy = __fsub_rn(py, by), bpz = __fsub_rn(pz, bz);
            const float d3 = __fadd_rn(__fadd_rn(__fmul_rn(abx, bpx), __fmul_rn(aby, bpy)), __fmul_rn(abz, bpz));
            const float d4 = __fadd_rn(__fadd_rn(__fmul_rn(acx, bpx), __fmul_rn(acy, bpy)), __fmul_rn(acz, bpz));
            const float cpx = __fsub_rn(px, cx), cpy = __fsub_rn(py, cy), cpz = __fsub_rn(pz, cz);
            const float d5 = __fadd_rn(__fadd_rn(__fmul_rn(abx, cpx), __fmul_rn(aby, cpy)), __fmul_rn(abz, cpz));
            const float d6 = __fadd_rn(__fadd_rn(__fmul_rn(acx, cpx), __fmul_rn(acy, cpy)), __fmul_rn(acz, cpz));

            const float vc_ = __fsub_rn(__fmul_rn(d1, d4), __fmul_rn(d3, d2));
            const float vb_ = __fsub_rn(__fmul_rn(d5, d2), __fmul_rn(d1, d6));
            const float va_ = __fsub_rn(__fmul_rn(d3, d6), __fmul_rn(d5, d4));

            const float den_ab = __fsub_rn(d1, d3);
            const float den_ac = __fsub_rn(d2, d6);
            const float t43    = __fsub_rn(d4, d3);
            const float t56    = __fsub_rn(d5, d6);
            const float den_bc = __fadd_rn(t43, t56);
            const float den_in = __fadd_rn(__fadd_rn(va_, vb_), vc_);

            // Region flags (reference where-chain priority: a>b>c>ab>ac>bc>interior)
            const bool f_a  = (d1 <= 0.0f) && (d2 <= 0.0f);
            const bool f_b  = (d3 >= 0.0f) && (d4 <= d3);
            const bool f_c  = (d6 >= 0.0f) && (d5 <= d6);
            const bool f_ab = (vc_ <= 0.0f) && (d1 >= 0.0f) && (d3 <= 0.0f);
            const bool f_ac = (vb_ <= 0.0f) && (d2 >= 0.0f) && (d6 <= 0.0f);
            const bool f_bc = (va_ <= 0.0f) && (t43 >= 0.0f) && (t56 >= 0.0f);
            const bool vert = f_a || f_b || f_c;
            const bool e_ab = f_ab && !vert;
            const bool e_ac = f_ac && !vert && !f_ab;
            const bool e_bc = f_bc && !vert && !f_ab && !f_ac;
            const bool inte = !vert && !f_ab && !f_ac && !f_bc;

            // Single division: surviving region's num/den (same rounding as ref).
            const float num  = e_ab ? d1 : (e_ac ? d2 : (e_bc ? t43 : 1.0f));
            const float denr = e_ab ? den_ab : (e_ac ? den_ac : (e_bc ? den_bc : den_in));
            const float den  = (denr != 0.0f) ? denr : 1.0f;
            const float t    = __fdiv_rn(num, den);

            const float v_in = __fmul_rn(vb_, t);
            const float w_in = __fmul_rn(vc_, t);

            // Unified q = base + e1*s1 + ac*s2 (selected path rounding == ref;
            // inactive terms contribute +/-0 which cannot change (p-q)^2).
            const float s1 = vert ? 0.0f : (inte ? v_in : t);
            const float s2 = inte ? w_in : 0.0f;
            const bool  sel_b = (!f_a && f_b) || e_bc;
            const bool  sel_c = !f_a && !f_b && f_c;
            const float e1x = e_ac ? acx : (e_bc ? cbx : abx);
            const float e1y = e_ac ? acy : (e_bc ? cby : aby);
            const float e1z = e_ac ? acz : (e_bc ? cbz : abz);
            const float bsx = sel_b ? bx : (sel_c ? cx : ax);
            const float bsy = sel_b ? by : (sel_c ? cy : ay);
            const float bsz = sel_b ? bz : (sel_c ? cz : az);
            const float qx = __fadd_rn(__fadd_rn(bsx, __fmul_rn(e1x, s1)), __fmul_rn(acx, s2));
            const float qy = __fadd_rn(__fadd_rn(bsy, __fmul_rn(e1y, s1)), __fmul_rn(acy, s2));
            const float qz = __fadd_rn(__fadd_rn(bsz, __fmul_rn(e1z, s1)), __fmul_rn(acz, s2));

            const float dxx = __fsub_rn(px, qx), dyy = __fsub_rn(py, qy), dzz = __fsub_rn(pz, qz);
            const float dist = __fadd_rn(__fadd_rn(__fmul_rn(dxx, dxx), __fmul_rn(dyy, dyy)), __fmul_rn(dzz, dzz));

            if (dist < bestd) {
                bestd = dist; besti = fbase + t0 + j;
                pruneS = fminf(pruneS, sqrtf(dist));
                pThr   = __fmaf_rn(pruneS, 1.0002f, 1e-5f);
            }
        }
    }

    const unsigned long long packed =
        ((unsigned long long)__float_as_uint(bestd) << 32) | (unsigned int)besti;
    atomicMin(&best[pid], packed);
}

__global__ __launch_bounds__(BLOCK) void sdf_final_kernel(
    const unsigned long long* __restrict__ best, float* __restrict__ out)
{
    __shared__ float wsum[BLOCK / 64];
    const int p = blockIdx.x * BLOCK + threadIdx.x;
    const unsigned long long v = best[p];
    const float d = __uint_as_float((unsigned)(v >> 32));
    const int idx = (int)(unsigned)(v & 0xffffffffull);
    out[1 + p] = d;
    out[1 + PTOT + p] = (float)idx;

    float s = d;
    for (int off = 32; off > 0; off >>= 1) s += __shfl_down(s, off, 64);
    const int lane = threadIdx.x & 63;
    const int w = threadIdx.x >> 6;
    if (lane == 0) wsum[w] = s;
    __syncthreads();
    if (threadIdx.x == 0) {
        float tsum = 0.0f;
        for (int i = 0; i < BLOCK / 64; ++i) tsum += wsum[i];
        atomicAdd(&out[0], tsum);
    }
}

extern "C" void kernel_launch(void* const* d_in, const int* in_sizes, int n_in,
                              void* d_out, int out_size, void* d_ws, size_t ws_size,
                              hipStream_t stream) {
    const float* verts  = (const float*)d_in[0];
    const int*   faces  = (const int*)d_in[1];
    const float* points = (const float*)d_in[2];
    float* out = (float*)d_out;

    char* ws = (char*)d_ws;
    unsigned long long* best = (unsigned long long*)(ws + WS_BEST);
    uint4*    sorted = (uint4*)(ws + WS_SORTED);
    unsigned* hist   = (unsigned*)(ws + WS_HIST);

    hipMemsetAsync(best, 0xFF, (size_t)PTOT * sizeof(unsigned long long), stream);
    hipMemsetAsync(hist, 0, (size_t)NBINS * sizeof(unsigned), stream);
    hipMemsetAsync(out, 0, sizeof(float), stream);  // loss accumulator

    hist_kernel<<<PTOT / BLOCK, BLOCK, 0, stream>>>(points, hist);
    scan_kernel<<<1, 256, 0, stream>>>(hist);
    scatter_kernel<<<PTOT / BLOCK, BLOCK, 0, stream>>>(points, hist, sorted);

    dim3 grid(PTOT / BLOCK, NCHUNK);
    sdf_main_kernel<<<grid, BLOCK, 0, stream>>>(verts, faces, sorted, best);
    sdf_final_kernel<<<PTOT / BLOCK, BLOCK, 0, stream>>>(best, out);
}